// Round 10
// baseline (186.712 us; speedup 1.0000x reference)
//
#include <hip/hip_runtime.h>
#include <hip/hip_bf16.h>

typedef __attribute__((ext_vector_type(8))) short bf16x8;
typedef __attribute__((ext_vector_type(4))) float f32x4;
typedef __attribute__((ext_vector_type(16))) float f32x16;
typedef __attribute__((ext_vector_type(4))) unsigned short u16x4;
typedef __attribute__((ext_vector_type(8))) unsigned short u16x8v;

#define S_LEN 2048
#define NHEAD 16
#define HDIM 64
#define DIM 1024

__device__ __forceinline__ unsigned short f2bf(float f) {
    union { float f; unsigned u; } x; x.f = f;
    unsigned r = x.u + 0x7FFFu + ((x.u >> 16) & 1u);
    return (unsigned short)(r >> 16);
}
__device__ __forceinline__ unsigned short f2bf_fast(float f) {
    union { float f; unsigned u; } x; x.f = f;
    return (unsigned short)((x.u + 0x8000u) >> 16);
}

__device__ __forceinline__ f32x4 mfma16(bf16x8 a, bf16x8 b, f32x4 c) {
    return __builtin_amdgcn_mfma_f32_16x16x32_bf16(a, b, c, 0, 0, 0);
}
__device__ __forceinline__ f32x16 mfma32(bf16x8 a, bf16x8 b, f32x16 c) {
    return __builtin_amdgcn_mfma_f32_32x32x16_bf16(a, b, c, 0, 0, 0);
}

__device__ __forceinline__ float fexp2(float x) {
#if __has_builtin(__builtin_amdgcn_exp2f)
    return __builtin_amdgcn_exp2f(x);
#else
    return exp2f(x);
#endif
}

__device__ __forceinline__ void gl_lds16(const void* g, void* l) {
    __builtin_amdgcn_global_load_lds(
        (const __attribute__((address_space(1))) unsigned int*)g,
        (__attribute__((address_space(3))) unsigned int*)l, 16, 0, 0);
}

// ---------- x fp32 -> bf16 ----------
__global__ __launch_bounds__(256) void xconv_kernel(const float* __restrict__ X,
                                                    unsigned short* __restrict__ Xb) {
    size_t i = ((size_t)blockIdx.x * 256 + threadIdx.x) * 8;
    float4 a = *reinterpret_cast<const float4*>(&X[i]);
    float4 b = *reinterpret_cast<const float4*>(&X[i + 4]);
    u16x8v o;
    o[0] = f2bf(a.x); o[1] = f2bf(a.y); o[2] = f2bf(a.z); o[3] = f2bf(a.w);
    o[4] = f2bf(b.x); o[5] = f2bf(b.y); o[6] = f2bf(b.z); o[7] = f2bf(b.w);
    *reinterpret_cast<u16x8v*>(&Xb[i]) = o;
}

// ---------- weight transpose + bf16 convert: W[K][N] -> Wt[N][K] ----------
__global__ __launch_bounds__(256) void wtrans_kernel(const float* __restrict__ W,
                                                     unsigned short* __restrict__ Wt,
                                                     int K, int N) {
    __shared__ float lds[64][65];
    int k0 = blockIdx.x * 64, n0 = blockIdx.y * 64;
    int tid = threadIdx.x;
    for (int idx = tid; idx < 1024; idx += 256) {
        int row = idx >> 4, c = (idx & 15) << 2;
        float4 v = *reinterpret_cast<const float4*>(&W[(size_t)(k0 + row) * N + n0 + c]);
        lds[row][c] = v.x; lds[row][c + 1] = v.y; lds[row][c + 2] = v.z; lds[row][c + 3] = v.w;
    }
    __syncthreads();
    for (int idx = tid; idx < 1024; idx += 256) {
        int row = idx >> 4, c = (idx & 15) << 2;
        u16x4 o;
        o[0] = f2bf(lds[c][row]);     o[1] = f2bf(lds[c + 1][row]);
        o[2] = f2bf(lds[c + 2][row]); o[3] = f2bf(lds[c + 3][row]);
        *reinterpret_cast<u16x4*>(&Wt[(size_t)(n0 + row) * K + k0 + c]) = o;
    }
}

// ---------- GEMM (m97 structure), unchanged ----------
template <int MODE>
__global__ __launch_bounds__(256) void gemm_kernel(
    const unsigned short* __restrict__ Ab, const unsigned short* __restrict__ Bt,
    const float* __restrict__ bias,
    unsigned short* __restrict__ Qb, unsigned short* __restrict__ Kb,
    unsigned short* __restrict__ Vt, float* __restrict__ outf) {
    __shared__ unsigned short Alds[128 * 64];
    __shared__ unsigned short Blds[128 * 64];
    const int tid = threadIdx.x;
    const int m0 = blockIdx.x * 128, n0 = blockIdx.y * 128;
    const int wid = tid >> 6, lane = tid & 63;
    const int wm = wid >> 1, wn = wid & 1;
    const int lr = lane & 15, lg = lane >> 4;

    const char* Abase = (const char*)(Ab + (size_t)m0 * 1024);
    const char* Bbase = (const char*)(Bt + (size_t)n0 * 1024);

    int srcOff[4], dstOff[4];
#pragma unroll
    for (int i = 0; i < 4; ++i) {
        int off = i * 4096 + wid * 1024 + lane * 16;
        int row = off >> 7, col = off & 127;
        srcOff[i] = row * 2048 + (col ^ ((row & 7) << 4));
        dstOff[i] = off;
    }
    const int swz = (lr & 7) << 4;

    f32x4 acc[4][4] = {};

    for (int kt = 0; kt < 16; ++kt) {
        __syncthreads();
#pragma unroll
        for (int i = 0; i < 4; ++i) {
            gl_lds16(Abase + srcOff[i] + kt * 128, (char*)Alds + dstOff[i]);
            gl_lds16(Bbase + srcOff[i] + kt * 128, (char*)Blds + dstOff[i]);
        }
        __syncthreads();

#pragma unroll
        for (int ks = 0; ks < 2; ++ks) {
            bf16x8 af[4], bfr[4];
#pragma unroll
            for (int i = 0; i < 4; ++i)
                af[i] = *reinterpret_cast<const bf16x8*>(
                    (const char*)Alds + (wm * 64 + i * 16 + lr) * 128 + ((ks * 64 + lg * 16) ^ swz));
#pragma unroll
            for (int j = 0; j < 4; ++j)
                bfr[j] = *reinterpret_cast<const bf16x8*>(
                    (const char*)Blds + (wn * 64 + j * 16 + lr) * 128 + ((ks * 64 + lg * 16) ^ swz));
            __builtin_amdgcn_s_setprio(1);
#pragma unroll
            for (int i = 0; i < 4; ++i)
#pragma unroll
                for (int j = 0; j < 4; ++j)
                    acc[i][j] = mfma16(af[i], bfr[j], acc[i][j]);
            __builtin_amdgcn_s_setprio(0);
        }
    }

    if constexpr (MODE == 0) {
        const int sec = n0 >> 10;
#pragma unroll
        for (int j = 0; j < 4; ++j) {
            int gn = n0 + wn * 64 + j * 16 + lr;
            float bv = bias[gn];
            int nn = gn & 1023, h = nn >> 6, d = nn & 63;
#pragma unroll
            for (int i = 0; i < 4; ++i) {
#pragma unroll
                for (int r = 0; r < 4; ++r) {
                    int m = m0 + wm * 64 + i * 16 + lg * 4 + r;
                    int b_ = m >> 11, s_ = m & 2047;
                    size_t bh = (size_t)(b_ * NHEAD + h);
                    float v = acc[i][j][r] + bv;
                    if (sec == 0)
                        Qb[(bh * S_LEN + s_) * HDIM + d] = f2bf(v * 0.18033688f);  // 1/8 * log2(e)
                    else if (sec == 1)
                        Kb[(bh * S_LEN + s_) * HDIM + d] = f2bf(v);
                    else
                        Vt[(bh * HDIM + d) * S_LEN + s_] = f2bf(v);
                }
            }
        }
    } else {
#pragma unroll
        for (int j = 0; j < 4; ++j) {
            int gn = n0 + wn * 64 + j * 16 + lr;
            float bv = bias[gn];
#pragma unroll
            for (int i = 0; i < 4; ++i) {
#pragma unroll
                for (int r = 0; r < 4; ++r) {
                    int m = m0 + wm * 64 + i * 16 + lg * 4 + r;
                    outf[(size_t)m * DIM + gn] = acc[i][j][r] + bv;
                }
            }
        }
    }
}

// ---------- flash attention: barrier-free, register-direct K/V from L2 ----------
// K/V are L2-resident after XCD swizzle (R9: FETCH 12MB). m169 pattern: drop LDS
// staging entirely; per-lane fragment loads straight to VGPRs, double-buffered
// one 32-key tile ahead (named reg sets, rule #20). No __syncthreads in kernel.
__device__ __forceinline__ void attn_step(const bf16x8 (&kr)[4], const bf16x8 (&vr)[4],
                                          const bf16x8 (&qf)[4], float& ls, f32x16 (&acc)[2]) {
    // QK^T swapped: A=K(32 keys), B=Q(32 q) -> lane holds q=l31,
    // keys k = (r&3) + 4*hi + 8*(r>>2)
    f32x16 p = {};
#pragma unroll
    for (int kst = 0; kst < 4; ++kst) p = mfma32(kr[kst], qf[kst], p);
#pragma unroll
    for (int r = 0; r < 16; ++r) { float e = fexp2(p[r]); p[r] = e; ls += e; }
    // repack: pa[k2][j] = P[q=l31][k = k2*16 + hi*8 + j]
    bf16x8 pa[2];
#pragma unroll
    for (int k2 = 0; k2 < 2; ++k2) {
        const int rb = 8 * k2;
        unsigned aw[2], bw[2];
#pragma unroll
        for (int u = 0; u < 2; ++u) {
            unsigned a, b;
            asm("v_cvt_pk_bf16_f32 %0, %1, %2"
                : "=v"(a) : "v"(p[rb + 2 * u]), "v"(p[rb + 2 * u + 1]));
            asm("v_cvt_pk_bf16_f32 %0, %1, %2"
                : "=v"(b) : "v"(p[rb + 4 + 2 * u]), "v"(p[rb + 4 + 2 * u + 1]));
            asm volatile("v_permlane32_swap_b32 %0, %1" : "+v"(a), "+v"(b));
            aw[u] = a; bw[u] = b;
        }
        union { unsigned w[4]; bf16x8 v; } pu;
        pu.w[0] = aw[0]; pu.w[1] = aw[1]; pu.w[2] = bw[0]; pu.w[3] = bw[1];
        pa[k2] = pu.v;
    }
#pragma unroll
    for (int dt = 0; dt < 2; ++dt)
#pragma unroll
        for (int k2 = 0; k2 < 2; ++k2)
            acc[dt] = mfma32(pa[k2], vr[dt * 2 + k2], acc[dt]);
}

__global__ __launch_bounds__(256) void attn_kernel(const unsigned short* __restrict__ Qb,
                                                   const unsigned short* __restrict__ Kb,
                                                   const unsigned short* __restrict__ Vt,
                                                   unsigned short* __restrict__ Ob) {
    const int L = blockIdx.x;                     // 0..511
    const int xcd = L & 7, slot = L >> 3;
    const int bh = xcd + 8 * (slot & 3);          // 4 heads per XCD -> K/V L2-resident
    const int qblk = slot >> 2;                   // 0..15
    const int wid = threadIdx.x >> 6;
    const int lane = threadIdx.x & 63;
    const int l31 = lane & 31, hi = lane >> 5;
    const int q0 = qblk * 128 + wid * 32;

    // Q fragments (scale*log2e folded upstream)
    const unsigned short* qrow = &Qb[((size_t)bh * S_LEN + q0 + l31) * HDIM];
    bf16x8 qf[4];
#pragma unroll
    for (int kst = 0; kst < 4; ++kst)
        qf[kst] = *reinterpret_cast<const bf16x8*>(&qrow[kst * 16 + hi * 8]);

    const char* kT = (const char*)&Kb[(size_t)bh * S_LEN * HDIM];  // 32-key tile at +jt*4096
    const char* vT = (const char*)&Vt[(size_t)bh * HDIM * S_LEN];  // 32-key tile at +jt*64

    // per-lane fragment offsets (32-key tile):
    //   K frag c=kst:      key=l31,       feat bytes c*32 + hi*16   (row 128B)
    //   V frag c=dt*2+k2:  d=(c>>1)*32+l31, key bytes (c&1)*32 + hi*16 (row 4096B)
    int kofs[4], vofs[4];
#pragma unroll
    for (int c = 0; c < 4; ++c) {
        kofs[c] = l31 * 128 + c * 32 + hi * 16;
        vofs[c] = ((c >> 1) * 32 + l31) * 4096 + (c & 1) * 32 + hi * 16;
    }

    float ls = 0.f;                                // per-lane partial row-sum (q = l31)
    f32x16 acc[2] = {};

    bf16x8 kA[4], vA[4], kB[4], vB[4];
#pragma unroll
    for (int c = 0; c < 4; ++c) {
        kA[c] = *reinterpret_cast<const bf16x8*>(kT + kofs[c]);
        vA[c] = *reinterpret_cast<const bf16x8*>(vT + vofs[c]);
    }

    for (int jt = 0; jt < 64; jt += 2) {
        {   // prefetch tile jt+1 -> B (jt+1 <= 63 always)
            const char* kp = kT + (jt + 1) * 4096;
            const char* vp = vT + (jt + 1) * 64;
#pragma unroll
            for (int c = 0; c < 4; ++c) {
                kB[c] = *reinterpret_cast<const bf16x8*>(kp + kofs[c]);
                vB[c] = *reinterpret_cast<const bf16x8*>(vp + vofs[c]);
            }
        }
        attn_step(kA, vA, qf, ls, acc);
        if (jt + 2 < 64) {   // prefetch tile jt+2 -> A
            const char* kp = kT + (jt + 2) * 4096;
            const char* vp = vT + (jt + 2) * 64;
#pragma unroll
            for (int c = 0; c < 4; ++c) {
                kA[c] = *reinterpret_cast<const bf16x8*>(kp + kofs[c]);
                vA[c] = *reinterpret_cast<const bf16x8*>(vp + vofs[c]);
            }
        }
        attn_step(kB, vB, qf, ls, acc);
    }

    // partner lane holds the other half of q = l31's keys
    ls += __shfl_xor(ls, 32, 64);

    float inv[16];
#pragma unroll
    for (int r = 0; r < 16; ++r) {
        int rq = (r & 3) + 8 * (r >> 2) + 4 * hi;
        inv[r] = 1.f / __shfl(ls, rq, 64);
    }

    const int b_ = bh >> 4, h = bh & 15;
#pragma unroll
    for (int dt = 0; dt < 2; ++dt)
#pragma unroll
        for (int r = 0; r < 16; ++r) {
            int rq = (r & 3) + 8 * (r >> 2) + 4 * hi;
            float o = acc[dt][r] * inv[r];
            int q = q0 + rq;
            Ob[((size_t)(b_ * S_LEN + q)) * DIM + h * HDIM + dt * 32 + l31] = f2bf_fast(o);
        }
}

extern "C" void kernel_launch(void* const* d_in, const int* in_sizes, int n_in,
                              void* d_out, int out_size, void* d_ws, size_t ws_size,
                              hipStream_t stream) {
    const float* x      = (const float*)d_in[0];
    const float* qkv_w  = (const float*)d_in[1];
    const float* qkv_b  = (const float*)d_in[2];
    const float* proj_w = (const float*)d_in[3];
    const float* proj_b = (const float*)d_in[4];
    float* out = (float*)d_out;

    unsigned short* Wqkvt = (unsigned short*)d_ws;         // [3072][1024] bf16
    unsigned short* Wpt   = Wqkvt + 3072 * 1024;           // [1024][1024] bf16
    unsigned short* Qb    = Wpt + 1024 * 1024;             // [32][2048][64] bf16 (scale*log2e folded)
    unsigned short* Kb    = Qb + 32 * 2048 * 64;           // [32][2048][64]
    unsigned short* Vt    = Kb + 32 * 2048 * 64;           // [32][64][2048]
    unsigned short* Ob    = Vt + 32 * 2048 * 64;           // [4096][1024] bf16
    unsigned short* Xb    = Ob + 4096 * 1024;              // [4096][1024] bf16

    xconv_kernel<<<2048, 256, 0, stream>>>(x, Xb);
    wtrans_kernel<<<dim3(16, 48), 256, 0, stream>>>(qkv_w, Wqkvt, 1024, 3072);
    wtrans_kernel<<<dim3(16, 16), 256, 0, stream>>>(proj_w, Wpt, 1024, 1024);

    gemm_kernel<0><<<dim3(32, 24), 256, 0, stream>>>(Xb, Wqkvt, qkv_b, Qb, Kb, Vt, nullptr);
    attn_kernel<<<512, 256, 0, stream>>>(Qb, Kb, Vt, Ob);
    gemm_kernel<1><<<dim3(32, 8), 256, 0, stream>>>(Ob, Wpt, proj_b, nullptr, nullptr, nullptr, out);
}

// Round 11
// 120.857 us; speedup vs baseline: 1.5449x; 1.5449x over previous
//
#include <hip/hip_runtime.h>
#include <hip/hip_bf16.h>

typedef __attribute__((ext_vector_type(8))) short bf16x8;
typedef __attribute__((ext_vector_type(4))) float f32x4;
typedef __attribute__((ext_vector_type(16))) float f32x16;
typedef __attribute__((ext_vector_type(4))) unsigned short u16x4;
typedef __attribute__((ext_vector_type(8))) unsigned short u16x8v;

#define S_LEN 2048
#define NHEAD 16
#define HDIM 64
#define DIM 1024

__device__ __forceinline__ unsigned short f2bf(float f) {
    union { float f; unsigned u; } x; x.f = f;
    unsigned r = x.u + 0x7FFFu + ((x.u >> 16) & 1u);
    return (unsigned short)(r >> 16);
}
__device__ __forceinline__ unsigned short f2bf_fast(float f) {
    union { float f; unsigned u; } x; x.f = f;
    return (unsigned short)((x.u + 0x8000u) >> 16);
}

__device__ __forceinline__ f32x4 mfma16(bf16x8 a, bf16x8 b, f32x4 c) {
    return __builtin_amdgcn_mfma_f32_16x16x32_bf16(a, b, c, 0, 0, 0);
}
__device__ __forceinline__ f32x16 mfma32(bf16x8 a, bf16x8 b, f32x16 c) {
    return __builtin_amdgcn_mfma_f32_32x32x16_bf16(a, b, c, 0, 0, 0);
}

__device__ __forceinline__ float fexp2(float x) {
#if __has_builtin(__builtin_amdgcn_exp2f)
    return __builtin_amdgcn_exp2f(x);
#else
    return exp2f(x);
#endif
}

__device__ __forceinline__ void gl_lds16(const void* g, void* l) {
    __builtin_amdgcn_global_load_lds(
        (const __attribute__((address_space(1))) unsigned int*)g,
        (__attribute__((address_space(3))) unsigned int*)l, 16, 0, 0);
}

// ---------- x fp32 -> bf16 ----------
__global__ __launch_bounds__(256) void xconv_kernel(const float* __restrict__ X,
                                                    unsigned short* __restrict__ Xb) {
    size_t i = ((size_t)blockIdx.x * 256 + threadIdx.x) * 8;
    float4 a = *reinterpret_cast<const float4*>(&X[i]);
    float4 b = *reinterpret_cast<const float4*>(&X[i + 4]);
    u16x8v o;
    o[0] = f2bf(a.x); o[1] = f2bf(a.y); o[2] = f2bf(a.z); o[3] = f2bf(a.w);
    o[4] = f2bf(b.x); o[5] = f2bf(b.y); o[6] = f2bf(b.z); o[7] = f2bf(b.w);
    *reinterpret_cast<u16x8v*>(&Xb[i]) = o;
}

// ---------- weight transpose + bf16 convert: W[K][N] -> Wt[N][K] ----------
__global__ __launch_bounds__(256) void wtrans_kernel(const float* __restrict__ W,
                                                     unsigned short* __restrict__ Wt,
                                                     int K, int N) {
    __shared__ float lds[64][65];
    int k0 = blockIdx.x * 64, n0 = blockIdx.y * 64;
    int tid = threadIdx.x;
    for (int idx = tid; idx < 1024; idx += 256) {
        int row = idx >> 4, c = (idx & 15) << 2;
        float4 v = *reinterpret_cast<const float4*>(&W[(size_t)(k0 + row) * N + n0 + c]);
        lds[row][c] = v.x; lds[row][c + 1] = v.y; lds[row][c + 2] = v.z; lds[row][c + 3] = v.w;
    }
    __syncthreads();
    for (int idx = tid; idx < 1024; idx += 256) {
        int row = idx >> 4, c = (idx & 15) << 2;
        u16x4 o;
        o[0] = f2bf(lds[c][row]);     o[1] = f2bf(lds[c + 1][row]);
        o[2] = f2bf(lds[c + 2][row]); o[3] = f2bf(lds[c + 3][row]);
        *reinterpret_cast<u16x4*>(&Wt[(size_t)(n0 + row) * K + k0 + c]) = o;
    }
}

// ---------- GEMM (m97 structure), unchanged ----------
template <int MODE>
__global__ __launch_bounds__(256) void gemm_kernel(
    const unsigned short* __restrict__ Ab, const unsigned short* __restrict__ Bt,
    const float* __restrict__ bias,
    unsigned short* __restrict__ Qb, unsigned short* __restrict__ Kb,
    unsigned short* __restrict__ Vt, float* __restrict__ outf) {
    __shared__ unsigned short Alds[128 * 64];
    __shared__ unsigned short Blds[128 * 64];
    const int tid = threadIdx.x;
    const int m0 = blockIdx.x * 128, n0 = blockIdx.y * 128;
    const int wid = tid >> 6, lane = tid & 63;
    const int wm = wid >> 1, wn = wid & 1;
    const int lr = lane & 15, lg = lane >> 4;

    const char* Abase = (const char*)(Ab + (size_t)m0 * 1024);
    const char* Bbase = (const char*)(Bt + (size_t)n0 * 1024);

    int srcOff[4], dstOff[4];
#pragma unroll
    for (int i = 0; i < 4; ++i) {
        int off = i * 4096 + wid * 1024 + lane * 16;
        int row = off >> 7, col = off & 127;
        srcOff[i] = row * 2048 + (col ^ ((row & 7) << 4));
        dstOff[i] = off;
    }
    const int swz = (lr & 7) << 4;

    f32x4 acc[4][4] = {};

    for (int kt = 0; kt < 16; ++kt) {
        __syncthreads();
#pragma unroll
        for (int i = 0; i < 4; ++i) {
            gl_lds16(Abase + srcOff[i] + kt * 128, (char*)Alds + dstOff[i]);
            gl_lds16(Bbase + srcOff[i] + kt * 128, (char*)Blds + dstOff[i]);
        }
        __syncthreads();

#pragma unroll
        for (int ks = 0; ks < 2; ++ks) {
            bf16x8 af[4], bfr[4];
#pragma unroll
            for (int i = 0; i < 4; ++i)
                af[i] = *reinterpret_cast<const bf16x8*>(
                    (const char*)Alds + (wm * 64 + i * 16 + lr) * 128 + ((ks * 64 + lg * 16) ^ swz));
#pragma unroll
            for (int j = 0; j < 4; ++j)
                bfr[j] = *reinterpret_cast<const bf16x8*>(
                    (const char*)Blds + (wn * 64 + j * 16 + lr) * 128 + ((ks * 64 + lg * 16) ^ swz));
            __builtin_amdgcn_s_setprio(1);
#pragma unroll
            for (int i = 0; i < 4; ++i)
#pragma unroll
                for (int j = 0; j < 4; ++j)
                    acc[i][j] = mfma16(af[i], bfr[j], acc[i][j]);
            __builtin_amdgcn_s_setprio(0);
        }
    }

    if constexpr (MODE == 0) {
        const int sec = n0 >> 10;
#pragma unroll
        for (int j = 0; j < 4; ++j) {
            int gn = n0 + wn * 64 + j * 16 + lr;
            float bv = bias[gn];
            int nn = gn & 1023, h = nn >> 6, d = nn & 63;
#pragma unroll
            for (int i = 0; i < 4; ++i) {
#pragma unroll
                for (int r = 0; r < 4; ++r) {
                    int m = m0 + wm * 64 + i * 16 + lg * 4 + r;
                    int b_ = m >> 11, s_ = m & 2047;
                    size_t bh = (size_t)(b_ * NHEAD + h);
                    float v = acc[i][j][r] + bv;
                    if (sec == 0)
                        Qb[(bh * S_LEN + s_) * HDIM + d] = f2bf(v * 0.18033688f);  // 1/8 * log2(e)
                    else if (sec == 1)
                        Kb[(bh * S_LEN + s_) * HDIM + d] = f2bf(v);
                    else
                        Vt[(bh * HDIM + d) * S_LEN + s_] = f2bf(v);
                }
            }
        }
    } else {
#pragma unroll
        for (int j = 0; j < 4; ++j) {
            int gn = n0 + wn * 64 + j * 16 + lr;
            float bv = bias[gn];
#pragma unroll
            for (int i = 0; i < 4; ++i) {
#pragma unroll
                for (int r = 0; r < 4; ++r) {
                    int m = m0 + wm * 64 + i * 16 + lg * 4 + r;
                    outf[(size_t)m * DIM + gn] = acc[i][j][r] + bv;
                }
            }
        }
    }
}

// ---------- flash attention: split-K waves, fragment-linear LDS, 2-tile intervals ----------
// Wave (qh=wid&1, kh=wid>>1): 64 q-rows x kh-half (32 keys) of each 64-key tile.
// K/V LDS reads per wave per tile halved to 8 b128 vs R9. Partials combined via
// LDS once at the end. Fragment-linear chunks (0 conflicts) + XCD swizzle kept.
// repack helper: p (16 f32, 32-key step) -> pa[2] A-frags (verified R10 path).
__device__ __forceinline__ void repack32(const f32x16& p, bf16x8 (&pa)[2]) {
#pragma unroll
    for (int k2 = 0; k2 < 2; ++k2) {
        const int rb = 8 * k2;
        unsigned aw[2], bw[2];
#pragma unroll
        for (int u = 0; u < 2; ++u) {
            unsigned a, b;
            asm("v_cvt_pk_bf16_f32 %0, %1, %2"
                : "=v"(a) : "v"(p[rb + 2 * u]), "v"(p[rb + 2 * u + 1]));
            asm("v_cvt_pk_bf16_f32 %0, %1, %2"
                : "=v"(b) : "v"(p[rb + 4 + 2 * u]), "v"(p[rb + 4 + 2 * u + 1]));
            asm volatile("v_permlane32_swap_b32 %0, %1" : "+v"(a), "+v"(b));
            aw[u] = a; bw[u] = b;
        }
        union { unsigned w[4]; bf16x8 v; } pu;
        pu.w[0] = aw[0]; pu.w[1] = aw[1]; pu.w[2] = bw[0]; pu.w[3] = bw[1];
        pa[k2] = pu.v;
    }
}

#define NPAIR 16   // 16 pairs x 128 keys = 2048
__global__ __launch_bounds__(256) void attn_kernel(const unsigned short* __restrict__ Qb,
                                                   const unsigned short* __restrict__ Kb,
                                                   const unsigned short* __restrict__ Vt,
                                                   unsigned short* __restrict__ Ob) {
    __shared__ char smem[65536];                  // 2 bufs x (16KB K + 16KB V)
    const int L = blockIdx.x;                     // 0..511
    const int xcd = L & 7, slot = L >> 3;
    const int bh = xcd + 8 * (slot & 3);          // 4 heads per XCD -> K/V L2-resident
    const int qblk = slot >> 2;                   // 0..15
    const int wid = threadIdx.x >> 6;
    const int lane = threadIdx.x & 63;
    const int l31 = lane & 31, hi = lane >> 5;
    const int qh = wid & 1, kh = wid >> 1;
    const int q0 = qblk * 128 + qh * 64;

    // Q fragments, 2 subtiles of 32 q (scale*log2e folded upstream)
    bf16x8 qf[2][4];
#pragma unroll
    for (int s = 0; s < 2; ++s) {
        const unsigned short* qrow = &Qb[((size_t)bh * S_LEN + q0 + s * 32 + l31) * HDIM];
#pragma unroll
        for (int kst = 0; kst < 4; ++kst)
            qf[s][kst] = *reinterpret_cast<const bf16x8*>(&qrow[kst * 16 + hi * 8]);
    }

    const char* kT = (const char*)&Kb[(size_t)bh * S_LEN * HDIM];  // tile t at +t*8192
    const char* vT = (const char*)&Vt[(size_t)bh * HDIM * S_LEN];  // tile t at +t*128

    // staging: wave stages chunk ids 8*wid..8*wid+7 (0-15 K, 16-31 V), 1KB each.
    // K id: t2=id>>3, khs=(id>>2)&1, kst=id&3 ; V id-16: t2,khs,dt,k2 bits.
    const char* sbase = (wid < 2) ? kT : vT;
    const int pairStride = (wid < 2) ? 16384 : 256;
    int srcOff[8], dstOff[8];
#pragma unroll
    for (int i = 0; i < 8; ++i) {
        int id = 8 * wid + i;
        if (id < 16) {
            int t2 = (id >> 3) & 1, khs = (id >> 2) & 1, kst = id & 3;
            srcOff[i] = t2 * 8192 + (khs * 32 + l31) * 128 + kst * 32 + hi * 16;
        } else {
            int c = id - 16;
            int t2 = (c >> 3) & 1, khs = (c >> 2) & 1, dt = (c >> 1) & 1, k2 = c & 1;
            srcOff[i] = t2 * 128 + (dt * 32 + l31) * 4096 + khs * 64 + k2 * 32 + hi * 16;
        }
        dstOff[i] = id * 1024;
    }

    float ls0 = 0.f, ls1 = 0.f;
    f32x16 acc[2][2] = {};

    // prologue: stage pair 0 -> buf 0
#pragma unroll
    for (int i = 0; i < 8; ++i)
        gl_lds16(sbase + srcOff[i], smem + dstOff[i]);
    __syncthreads();

    int cur = 0;
    for (int pt = 0; pt < NPAIR; ++pt) {
        if (pt + 1 < NPAIR) {
#pragma unroll
            for (int i = 0; i < 8; ++i)
                gl_lds16(sbase + (pt + 1) * pairStride + srcOff[i],
                         smem + (cur ^ 1) * 32768 + dstOff[i]);
        }
#pragma unroll
        for (int t2 = 0; t2 < 2; ++t2) {
            const char* kbb = smem + cur * 32768 + (t2 * 8 + kh * 4) * 1024 + lane * 16;
            const char* vbb = smem + cur * 32768 + 16384 + (t2 * 8 + kh * 4) * 1024 + lane * 16;
            bf16x8 kb[4];
#pragma unroll
            for (int kst = 0; kst < 4; ++kst)
                kb[kst] = *reinterpret_cast<const bf16x8*>(kbb + kst * 1024);

            // QK^T swapped, both q-subtiles share kb. lane holds q=l31,
            // local key = (r&3) + 4*hi + 8*(r>>2)
            f32x16 p0 = {}, p1 = {};
            __builtin_amdgcn_s_setprio(1);
#pragma unroll
            for (int kst = 0; kst < 4; ++kst) p0 = mfma32(kb[kst], qf[0][kst], p0);
#pragma unroll
            for (int kst = 0; kst < 4; ++kst) p1 = mfma32(kb[kst], qf[1][kst], p1);
            __builtin_amdgcn_s_setprio(0);

#pragma unroll
            for (int r = 0; r < 16; ++r) {
                float e0 = fexp2(p0[r]); p0[r] = e0; ls0 += e0;
                float e1 = fexp2(p1[r]); p1[r] = e1; ls1 += e1;
            }
            bf16x8 paA[2], paB[2];
            repack32(p0, paA);
            repack32(p1, paB);

            // PV: each V chunk read once, feeds both subtiles
            __builtin_amdgcn_s_setprio(1);
#pragma unroll
            for (int dt = 0; dt < 2; ++dt)
#pragma unroll
                for (int k2 = 0; k2 < 2; ++k2) {
                    bf16x8 vb = *reinterpret_cast<const bf16x8*>(vbb + (dt * 2 + k2) * 1024);
                    acc[0][dt] = mfma32(paA[k2], vb, acc[0][dt]);
                    acc[1][dt] = mfma32(paB[k2], vb, acc[1][dt]);
                }
            __builtin_amdgcn_s_setprio(0);
        }
        __syncthreads();   // staging complete for next pair + buf reuse safe
        cur ^= 1;
    }

    // combine hi-halves within wave (full 32-key-half sums per q)
    ls0 += __shfl_xor(ls0, 32, 64);
    ls1 += __shfl_xor(ls1, 32, 64);

    // cross-wave combine (key halves) through LDS; kh=1 writes, kh=0 reduces
    float* cacc = (float*)smem;                       // [qh][s*2+dt][r][lane] f32
    float* cls  = (float*)(smem + 32768);             // [qh][s][l31]
    if (kh == 1) {
#pragma unroll
        for (int s = 0; s < 2; ++s)
#pragma unroll
            for (int dt = 0; dt < 2; ++dt)
#pragma unroll
                for (int r = 0; r < 16; ++r)
                    cacc[qh * 4096 + (s * 2 + dt) * 1024 + r * 64 + lane] = acc[s][dt][r];
        cls[qh * 128 + l31] = ls0;
        cls[qh * 128 + 64 + l31] = ls1;
    }
    __syncthreads();
    if (kh == 0) {
        ls0 += cls[qh * 128 + l31];
        ls1 += cls[qh * 128 + 64 + l31];
#pragma unroll
        for (int s = 0; s < 2; ++s)
#pragma unroll
            for (int dt = 0; dt < 2; ++dt)
#pragma unroll
                for (int r = 0; r < 16; ++r)
                    acc[s][dt][r] += cacc[qh * 4096 + (s * 2 + dt) * 1024 + r * 64 + lane];

        const int b_ = bh >> 4, h = bh & 15;
        float inv0[16], inv1[16];
#pragma unroll
        for (int r = 0; r < 16; ++r) {
            int rq = (r & 3) + 8 * (r >> 2) + 4 * hi;
            inv0[r] = 1.f / __shfl(ls0, rq, 64);
            inv1[r] = 1.f / __shfl(ls1, rq, 64);
        }
#pragma unroll
        for (int dt = 0; dt < 2; ++dt)
#pragma unroll
            for (int r = 0; r < 16; ++r) {
                int rq = (r & 3) + 8 * (r >> 2) + 4 * hi;
                int q0s = q0 + rq;
                Ob[((size_t)(b_ * S_LEN + q0s)) * DIM + h * HDIM + dt * 32 + l31] =
                    f2bf_fast(acc[0][dt][r] * inv0[r]);
                Ob[((size_t)(b_ * S_LEN + q0s + 32)) * DIM + h * HDIM + dt * 32 + l31] =
                    f2bf_fast(acc[1][dt][r] * inv1[r]);
            }
    }
}

extern "C" void kernel_launch(void* const* d_in, const int* in_sizes, int n_in,
                              void* d_out, int out_size, void* d_ws, size_t ws_size,
                              hipStream_t stream) {
    const float* x      = (const float*)d_in[0];
    const float* qkv_w  = (const float*)d_in[1];
    const float* qkv_b  = (const float*)d_in[2];
    const float* proj_w = (const float*)d_in[3];
    const float* proj_b = (const float*)d_in[4];
    float* out = (float*)d_out;

    unsigned short* Wqkvt = (unsigned short*)d_ws;         // [3072][1024] bf16
    unsigned short* Wpt   = Wqkvt + 3072 * 1024;           // [1024][1024] bf16
    unsigned short* Qb    = Wpt + 1024 * 1024;             // [32][2048][64] bf16 (scale*log2e folded)
    unsigned short* Kb    = Qb + 32 * 2048 * 64;           // [32][2048][64]
    unsigned short* Vt    = Kb + 32 * 2048 * 64;           // [32][64][2048]
    unsigned short* Ob    = Vt + 32 * 2048 * 64;           // [4096][1024] bf16
    unsigned short* Xb    = Ob + 4096 * 1024;              // [4096][1024] bf16

    xconv_kernel<<<2048, 256, 0, stream>>>(x, Xb);
    wtrans_kernel<<<dim3(16, 48), 256, 0, stream>>>(qkv_w, Wqkvt, 1024, 3072);
    wtrans_kernel<<<dim3(16, 16), 256, 0, stream>>>(proj_w, Wpt, 1024, 1024);

    gemm_kernel<0><<<dim3(32, 24), 256, 0, stream>>>(Xb, Wqkvt, qkv_b, Qb, Kb, Vt, nullptr);
    attn_kernel<<<512, 256, 0, stream>>>(Qb, Kb, Vt, Ob);
    gemm_kernel<1><<<dim3(32, 8), 256, 0, stream>>>(Ob, Wpt, proj_b, nullptr, nullptr, nullptr, out);
}

// Round 12
// 114.471 us; speedup vs baseline: 1.6311x; 1.0558x over previous
//
#include <hip/hip_runtime.h>
#include <hip/hip_bf16.h>

typedef __attribute__((ext_vector_type(8))) short bf16x8;
typedef __attribute__((ext_vector_type(4))) float f32x4;
typedef __attribute__((ext_vector_type(16))) float f32x16;
typedef __attribute__((ext_vector_type(4))) unsigned short u16x4;
typedef __attribute__((ext_vector_type(8))) unsigned short u16x8v;

#define S_LEN 2048
#define NHEAD 16
#define HDIM 64
#define DIM 1024

__device__ __forceinline__ unsigned short f2bf(float f) {
    union { float f; unsigned u; } x; x.f = f;
    unsigned r = x.u + 0x7FFFu + ((x.u >> 16) & 1u);
    return (unsigned short)(r >> 16);
}
__device__ __forceinline__ unsigned short f2bf_fast(float f) {
    union { float f; unsigned u; } x; x.f = f;
    return (unsigned short)((x.u + 0x8000u) >> 16);
}

__device__ __forceinline__ f32x4 mfma16(bf16x8 a, bf16x8 b, f32x4 c) {
    return __builtin_amdgcn_mfma_f32_16x16x32_bf16(a, b, c, 0, 0, 0);
}
__device__ __forceinline__ f32x16 mfma32(bf16x8 a, bf16x8 b, f32x16 c) {
    return __builtin_amdgcn_mfma_f32_32x32x16_bf16(a, b, c, 0, 0, 0);
}

__device__ __forceinline__ float fexp2(float x) {
#if __has_builtin(__builtin_amdgcn_exp2f)
    return __builtin_amdgcn_exp2f(x);
#else
    return exp2f(x);
#endif
}

__device__ __forceinline__ void gl_lds16(const void* g, void* l) {
    __builtin_amdgcn_global_load_lds(
        (const __attribute__((address_space(1))) unsigned int*)g,
        (__attribute__((address_space(3))) unsigned int*)l, 16, 0, 0);
}

// ---------- x fp32 -> bf16 ----------
__global__ __launch_bounds__(256) void xconv_kernel(const float* __restrict__ X,
                                                    unsigned short* __restrict__ Xb) {
    size_t i = ((size_t)blockIdx.x * 256 + threadIdx.x) * 8;
    float4 a = *reinterpret_cast<const float4*>(&X[i]);
    float4 b = *reinterpret_cast<const float4*>(&X[i + 4]);
    u16x8v o;
    o[0] = f2bf(a.x); o[1] = f2bf(a.y); o[2] = f2bf(a.z); o[3] = f2bf(a.w);
    o[4] = f2bf(b.x); o[5] = f2bf(b.y); o[6] = f2bf(b.z); o[7] = f2bf(b.w);
    *reinterpret_cast<u16x8v*>(&Xb[i]) = o;
}

// ---------- weight transpose + bf16 convert: W[K][N] -> Wt[N][K] ----------
__global__ __launch_bounds__(256) void wtrans_kernel(const float* __restrict__ W,
                                                     unsigned short* __restrict__ Wt,
                                                     int K, int N) {
    __shared__ float lds[64][65];
    int k0 = blockIdx.x * 64, n0 = blockIdx.y * 64;
    int tid = threadIdx.x;
    for (int idx = tid; idx < 1024; idx += 256) {
        int row = idx >> 4, c = (idx & 15) << 2;
        float4 v = *reinterpret_cast<const float4*>(&W[(size_t)(k0 + row) * N + n0 + c]);
        lds[row][c] = v.x; lds[row][c + 1] = v.y; lds[row][c + 2] = v.z; lds[row][c + 3] = v.w;
    }
    __syncthreads();
    for (int idx = tid; idx < 1024; idx += 256) {
        int row = idx >> 4, c = (idx & 15) << 2;
        u16x4 o;
        o[0] = f2bf(lds[c][row]);     o[1] = f2bf(lds[c + 1][row]);
        o[2] = f2bf(lds[c + 2][row]); o[3] = f2bf(lds[c + 3][row]);
        *reinterpret_cast<u16x4*>(&Wt[(size_t)(n0 + row) * K + k0 + c]) = o;
    }
}

// ---------- GEMM (m97 structure), unchanged ----------
template <int MODE>
__global__ __launch_bounds__(256) void gemm_kernel(
    const unsigned short* __restrict__ Ab, const unsigned short* __restrict__ Bt,
    const float* __restrict__ bias,
    unsigned short* __restrict__ Qb, unsigned short* __restrict__ Kb,
    unsigned short* __restrict__ Vt, float* __restrict__ outf) {
    __shared__ unsigned short Alds[128 * 64];
    __shared__ unsigned short Blds[128 * 64];
    const int tid = threadIdx.x;
    const int m0 = blockIdx.x * 128, n0 = blockIdx.y * 128;
    const int wid = tid >> 6, lane = tid & 63;
    const int wm = wid >> 1, wn = wid & 1;
    const int lr = lane & 15, lg = lane >> 4;

    const char* Abase = (const char*)(Ab + (size_t)m0 * 1024);
    const char* Bbase = (const char*)(Bt + (size_t)n0 * 1024);

    int srcOff[4], dstOff[4];
#pragma unroll
    for (int i = 0; i < 4; ++i) {
        int off = i * 4096 + wid * 1024 + lane * 16;
        int row = off >> 7, col = off & 127;
        srcOff[i] = row * 2048 + (col ^ ((row & 7) << 4));
        dstOff[i] = off;
    }
    const int swz = (lr & 7) << 4;

    f32x4 acc[4][4] = {};

    for (int kt = 0; kt < 16; ++kt) {
        __syncthreads();
#pragma unroll
        for (int i = 0; i < 4; ++i) {
            gl_lds16(Abase + srcOff[i] + kt * 128, (char*)Alds + dstOff[i]);
            gl_lds16(Bbase + srcOff[i] + kt * 128, (char*)Blds + dstOff[i]);
        }
        __syncthreads();

#pragma unroll
        for (int ks = 0; ks < 2; ++ks) {
            bf16x8 af[4], bfr[4];
#pragma unroll
            for (int i = 0; i < 4; ++i)
                af[i] = *reinterpret_cast<const bf16x8*>(
                    (const char*)Alds + (wm * 64 + i * 16 + lr) * 128 + ((ks * 64 + lg * 16) ^ swz));
#pragma unroll
            for (int j = 0; j < 4; ++j)
                bfr[j] = *reinterpret_cast<const bf16x8*>(
                    (const char*)Blds + (wn * 64 + j * 16 + lr) * 128 + ((ks * 64 + lg * 16) ^ swz));
            __builtin_amdgcn_s_setprio(1);
#pragma unroll
            for (int i = 0; i < 4; ++i)
#pragma unroll
                for (int j = 0; j < 4; ++j)
                    acc[i][j] = mfma16(af[i], bfr[j], acc[i][j]);
            __builtin_amdgcn_s_setprio(0);
        }
    }

    if constexpr (MODE == 0) {
        const int sec = n0 >> 10;
#pragma unroll
        for (int j = 0; j < 4; ++j) {
            int gn = n0 + wn * 64 + j * 16 + lr;
            float bv = bias[gn];
            int nn = gn & 1023, h = nn >> 6, d = nn & 63;
#pragma unroll
            for (int i = 0; i < 4; ++i) {
#pragma unroll
                for (int r = 0; r < 4; ++r) {
                    int m = m0 + wm * 64 + i * 16 + lg * 4 + r;
                    int b_ = m >> 11, s_ = m & 2047;
                    size_t bh = (size_t)(b_ * NHEAD + h);
                    float v = acc[i][j][r] + bv;
                    if (sec == 0)
                        Qb[(bh * S_LEN + s_) * HDIM + d] = f2bf(v * 0.18033688f);  // 1/8 * log2(e)
                    else if (sec == 1)
                        Kb[(bh * S_LEN + s_) * HDIM + d] = f2bf(v);
                    else
                        Vt[(bh * HDIM + d) * S_LEN + s_] = f2bf(v);
                }
            }
        }
    } else {
#pragma unroll
        for (int j = 0; j < 4; ++j) {
            int gn = n0 + wn * 64 + j * 16 + lr;
            float bv = bias[gn];
#pragma unroll
            for (int i = 0; i < 4; ++i) {
#pragma unroll
                for (int r = 0; r < 4; ++r) {
                    int m = m0 + wm * 64 + i * 16 + lg * 4 + r;
                    outf[(size_t)m * DIM + gn] = acc[i][j][r] + bv;
                }
            }
        }
    }
}

// ---------- flash attention: 8 waves (4q x 2k split), 4 waves/SIMD ----------
// Wave (qs=wid&3, kh=wid>>2): 32 q-rows x kh 32-key half of each 64-key tile.
// 4096 total waves -> 4/SIMD: phase drift overlaps exp2 (VALU) with MFMA.
// Fragment-linear LDS chunks (0 conflicts), XCD swizzle, 2-tile staging pairs.
__device__ __forceinline__ void repack32(const f32x16& p, bf16x8 (&pa)[2]) {
#pragma unroll
    for (int k2 = 0; k2 < 2; ++k2) {
        const int rb = 8 * k2;
        unsigned aw[2], bw[2];
#pragma unroll
        for (int u = 0; u < 2; ++u) {
            unsigned a, b;
            asm("v_cvt_pk_bf16_f32 %0, %1, %2"
                : "=v"(a) : "v"(p[rb + 2 * u]), "v"(p[rb + 2 * u + 1]));
            asm("v_cvt_pk_bf16_f32 %0, %1, %2"
                : "=v"(b) : "v"(p[rb + 4 + 2 * u]), "v"(p[rb + 4 + 2 * u + 1]));
            asm volatile("v_permlane32_swap_b32 %0, %1" : "+v"(a), "+v"(b));
            aw[u] = a; bw[u] = b;
        }
        union { unsigned w[4]; bf16x8 v; } pu;
        pu.w[0] = aw[0]; pu.w[1] = aw[1]; pu.w[2] = bw[0]; pu.w[3] = bw[1];
        pa[k2] = pu.v;
    }
}

#define NPAIR 16   // 16 pairs x 128 keys = 2048
__global__ __launch_bounds__(512, 4) void attn_kernel(const unsigned short* __restrict__ Qb,
                                                      const unsigned short* __restrict__ Kb,
                                                      const unsigned short* __restrict__ Vt,
                                                      unsigned short* __restrict__ Ob) {
    __shared__ char smem[65536];                  // 2 bufs x (16KB K + 16KB V)
    const int L = blockIdx.x;                     // 0..511
    const int xcd = L & 7, slot = L >> 3;
    const int bh = xcd + 8 * (slot & 3);          // 4 heads per XCD -> K/V L2-resident
    const int qblk = slot >> 2;                   // 0..15
    const int wid = threadIdx.x >> 6;             // 0..7
    const int lane = threadIdx.x & 63;
    const int l31 = lane & 31, hi = lane >> 5;
    const int qs = wid & 3, kh = wid >> 2;
    const int q0 = qblk * 128 + qs * 32;

    // Q fragments (scale*log2e folded upstream): frag[q=l31][feat=kst*16+hi*8+j]
    const unsigned short* qrow = &Qb[((size_t)bh * S_LEN + q0 + l31) * HDIM];
    bf16x8 qf[4];
#pragma unroll
    for (int kst = 0; kst < 4; ++kst)
        qf[kst] = *reinterpret_cast<const bf16x8*>(&qrow[kst * 16 + hi * 8]);

    const char* kT = (const char*)&Kb[(size_t)bh * S_LEN * HDIM];  // tile t at +t*8192
    const char* vT = (const char*)&Vt[(size_t)bh * HDIM * S_LEN];  // tile t at +t*128

    // staging: 32 chunks per pair (ids 0-15 K, 16-31 V), wave stages ids 4*wid..+3
    const char* sbase = (wid < 4) ? kT : vT;
    const int pairStride = (wid < 4) ? 16384 : 256;
    int srcOff[4], dstOff[4];
#pragma unroll
    for (int i = 0; i < 4; ++i) {
        int id = 4 * wid + i;
        if (id < 16) {
            int t2 = (id >> 3) & 1, khs = (id >> 2) & 1, kst = id & 3;
            srcOff[i] = t2 * 8192 + (khs * 32 + l31) * 128 + kst * 32 + hi * 16;
        } else {
            int c = id - 16;
            int t2 = (c >> 3) & 1, khs = (c >> 2) & 1, dt = (c >> 1) & 1, k2 = c & 1;
            srcOff[i] = t2 * 128 + (dt * 32 + l31) * 4096 + khs * 64 + k2 * 32 + hi * 16;
        }
        dstOff[i] = id * 1024;
    }

    float ls = 0.f;
    f32x16 acc[2] = {};

    // prologue: stage pair 0 -> buf 0
#pragma unroll
    for (int i = 0; i < 4; ++i)
        gl_lds16(sbase + srcOff[i], smem + dstOff[i]);
    __syncthreads();

    int cur = 0;
    for (int pt = 0; pt < NPAIR; ++pt) {
        if (pt + 1 < NPAIR) {
#pragma unroll
            for (int i = 0; i < 4; ++i)
                gl_lds16(sbase + (pt + 1) * pairStride + srcOff[i],
                         smem + (cur ^ 1) * 32768 + dstOff[i]);
        }
#pragma unroll
        for (int t2 = 0; t2 < 2; ++t2) {
            const char* kbb = smem + cur * 32768 + (t2 * 8 + kh * 4) * 1024 + lane * 16;
            const char* vbb = smem + cur * 32768 + 16384 + (t2 * 8 + kh * 4) * 1024 + lane * 16;

            // QK^T swapped: lane holds q=l31, local key = (r&3)+4*hi+8*(r>>2)
            f32x16 p = {};
            __builtin_amdgcn_s_setprio(1);
#pragma unroll
            for (int kst = 0; kst < 4; ++kst) {
                bf16x8 kb = *reinterpret_cast<const bf16x8*>(kbb + kst * 1024);
                p = mfma32(kb, qf[kst], p);
            }
            __builtin_amdgcn_s_setprio(0);

#pragma unroll
            for (int r = 0; r < 16; ++r) {
                float e = fexp2(p[r]); p[r] = e; ls += e;
            }
            bf16x8 pa[2];
            repack32(p, pa);

            __builtin_amdgcn_s_setprio(1);
#pragma unroll
            for (int dt = 0; dt < 2; ++dt)
#pragma unroll
                for (int k2 = 0; k2 < 2; ++k2) {
                    bf16x8 vb = *reinterpret_cast<const bf16x8*>(vbb + (dt * 2 + k2) * 1024);
                    acc[dt] = mfma32(pa[k2], vb, acc[dt]);
                }
            __builtin_amdgcn_s_setprio(0);
        }
        __syncthreads();   // staging complete for next pair + buf reuse safe
        cur ^= 1;
    }

    // combine hi halves: lane q=l31 now has sum over its 32-key half
    ls += __shfl_xor(ls, 32, 64);

    // cross-wave combine (key halves) via LDS; kh=1 writes, kh=0 reduces+stores
    float* cacc = (float*)smem;                   // [qs][dt][r][lane] f32 = 32KB
    float* cls  = (float*)(smem + 32768);         // [qs][l31]
    if (kh == 1) {
#pragma unroll
        for (int dt = 0; dt < 2; ++dt)
#pragma unroll
            for (int r = 0; r < 16; ++r)
                cacc[qs * 2048 + dt * 1024 + r * 64 + lane] = acc[dt][r];
        cls[qs * 32 + l31] = ls;                  // both hi lanes write same value
    }
    __syncthreads();
    if (kh == 0) {
        ls += cls[qs * 32 + l31];
#pragma unroll
        for (int dt = 0; dt < 2; ++dt)
#pragma unroll
            for (int r = 0; r < 16; ++r)
                acc[dt][r] += cacc[qs * 2048 + dt * 1024 + r * 64 + lane];

        const int b_ = bh >> 4, h = bh & 15;
        float inv[16];
#pragma unroll
        for (int r = 0; r < 16; ++r) {
            int rq = (r & 3) + 8 * (r >> 2) + 4 * hi;
            inv[r] = 1.f / __shfl(ls, rq, 64);
        }
#pragma unroll
        for (int dt = 0; dt < 2; ++dt)
#pragma unroll
            for (int r = 0; r < 16; ++r) {
                int rq = (r & 3) + 8 * (r >> 2) + 4 * hi;
                int q = q0 + rq;
                Ob[((size_t)(b_ * S_LEN + q)) * DIM + h * HDIM + dt * 32 + l31] =
                    f2bf_fast(acc[dt][r] * inv[r]);
            }
    }
}

extern "C" void kernel_launch(void* const* d_in, const int* in_sizes, int n_in,
                              void* d_out, int out_size, void* d_ws, size_t ws_size,
                              hipStream_t stream) {
    const float* x      = (const float*)d_in[0];
    const float* qkv_w  = (const float*)d_in[1];
    const float* qkv_b  = (const float*)d_in[2];
    const float* proj_w = (const float*)d_in[3];
    const float* proj_b = (const float*)d_in[4];
    float* out = (float*)d_out;

    unsigned short* Wqkvt = (unsigned short*)d_ws;         // [3072][1024] bf16
    unsigned short* Wpt   = Wqkvt + 3072 * 1024;           // [1024][1024] bf16
    unsigned short* Qb    = Wpt + 1024 * 1024;             // [32][2048][64] bf16 (scale*log2e folded)
    unsigned short* Kb    = Qb + 32 * 2048 * 64;           // [32][2048][64]
    unsigned short* Vt    = Kb + 32 * 2048 * 64;           // [32][64][2048]
    unsigned short* Ob    = Vt + 32 * 2048 * 64;           // [4096][1024] bf16
    unsigned short* Xb    = Ob + 4096 * 1024;              // [4096][1024] bf16

    xconv_kernel<<<2048, 256, 0, stream>>>(x, Xb);
    wtrans_kernel<<<dim3(16, 48), 256, 0, stream>>>(qkv_w, Wqkvt, 1024, 3072);
    wtrans_kernel<<<dim3(16, 16), 256, 0, stream>>>(proj_w, Wpt, 1024, 1024);

    gemm_kernel<0><<<dim3(32, 24), 256, 0, stream>>>(Xb, Wqkvt, qkv_b, Qb, Kb, Vt, nullptr);
    attn_kernel<<<512, 512, 0, stream>>>(Qb, Kb, Vt, Ob);
    gemm_kernel<1><<<dim3(32, 8), 256, 0, stream>>>(Ob, Wpt, proj_b, nullptr, nullptr, nullptr, out);
}